// Round 7
// baseline (448.221 us; speedup 1.0000x reference)
//
#include <hip/hip_runtime.h>
#include <cstdint>
#include <cstddef>

// Problem constants (from reference)
#define TOKENS 2048
#define IN_F   4096
#define OUT_F  11008
#define W_BIT  4
#define RANK   16
#define QWB    (OUT_F * IN_F / 8)   // 5,636,096 int32 "bytes" per bit-plane

typedef unsigned short ushort_t;
typedef __attribute__((ext_vector_type(8))) short   short8;   // 8 bf16 = 4 VGPRs (MFMA A/B frag)
typedef __attribute__((ext_vector_type(4))) float   floatx4;  // MFMA C/D frag

__device__ __forceinline__ ushort_t f2bf(float f) {
  union { float f; uint32_t u; } c; c.f = f;
  uint32_t r = c.u + 0x7FFFu + ((c.u >> 16) & 1u);  // RNE
  return (ushort_t)(r >> 16);
}

// async global->LDS, 16B per lane; lds pointer must be wave-uniform base (HW adds lane*16)
__device__ __forceinline__ void gl_lds16(const void* g, void* l) {
  __builtin_amdgcn_global_load_lds(
      (const __attribute__((address_space(1))) uint32_t*)g,
      (__attribute__((address_space(3))) uint32_t*)l, 16, 0, 0);
}

// ---------------- phase 0a: x fp32 -> bf16 ----------------
__global__ __launch_bounds__(256) void k_cvt_x(const float* __restrict__ x,
                                               ushort_t* __restrict__ xb) {
  int idx = blockIdx.x * 256 + threadIdx.x;
  float4 v = ((const float4*)x)[idx];
  ushort4 r;
  r.x = f2bf(v.x); r.y = f2bf(v.y); r.z = f2bf(v.z); r.w = f2bf(v.w);
  ((ushort4*)xb)[idx] = r;
}

// ---------------- phase 0b: u -> bf16 (same layout), vt -> bf16 transposed ----------------
#define N_U  (W_BIT * OUT_F * RANK)   // 704512
#define N_VT (W_BIT * RANK * IN_F)    // 262144
__global__ __launch_bounds__(256) void k_prep_uv(const float* __restrict__ u,
                                                 const float* __restrict__ vt,
                                                 ushort_t* __restrict__ ub,
                                                 ushort_t* __restrict__ vtT) {
  int idx = blockIdx.x * 256 + threadIdx.x;
  if (idx < N_U) {
    ub[idx] = f2bf(u[idx]);
  } else {
    int e = idx - N_U;                 // [0, N_VT)
    int b = e >> 16;                   // RANK*IN_F = 65536
    int r = e & 65535;
    int k = r >> 12;                   // IN_F = 4096
    int i = r & 4095;
    vtT[((size_t)b * IN_F + i) * RANK + k] = f2bf(vt[e]);
  }
}

// ---------------- phase 1: build w (bf16): MFMA product + LDS-staged sign apply ----
// Round-0 version, verbatim (best measured). Do NOT edit blind: two prior
// "optimizations" regressed the non-gemm time 206 -> 250 us; reverting recovered it.
__global__ __launch_bounds__(256) void k_build_w(const int* __restrict__ qw,
                                                 const ushort_t* __restrict__ ub,
                                                 const ushort_t* __restrict__ vtT,
                                                 ushort_t* __restrict__ w) {
  __shared__ int qs[W_BIT * 128 * 20];  // 40 KB
  const int tid = threadIdx.x;
  const int ob = blockIdx.x / (IN_F / 128);
  const int ib = blockIdx.x % (IN_F / 128);
  const int o0 = ob * 128, i0 = ib * 128;
  const int lane = tid & 63, wv = tid >> 6;
  const int wm = (wv >> 1) * 64, wn = (wv & 1) * 64;
  const int l16 = lane & 15, q = lane >> 4;
  const bool qlo = (q < 2);
  const int koff = (q & 1) * 8;        // valid k-halves for q=0,1; q>=2 zeroed
  const short8 zf = (short8)0;

  // stage qw tile: 4 planes x 128 rows x 16 ints; 2048 int4 chunks, 8/thread, coalesced
  #pragma unroll
  for (int n = 0; n < 8; ++n) {
    int c = n * 256 + tid;             // [0, 2048)
    int b = c >> 9, rem = c & 511;
    int row = rem >> 2, part = rem & 3;
    int4 v = *(const int4*)(qw + (size_t)b * QWB +
                            (size_t)(o0 + row) * (IN_F / 8) + (i0 >> 3) + part * 4);
    *(int4*)&qs[(b * 128 + row) * 20 + part * 4] = v;
  }

  floatx4 acc[16];
  #pragma unroll
  for (int i = 0; i < 16; ++i) acc[i] = (floatx4){0.f, 0.f, 0.f, 0.f};

  const int qc_base = (wn >> 3) + (l16 >> 3);  // LDS int col for this lane (+ni*2)
  const int bit = l16 & 7;

  __syncthreads();

  #pragma unroll
  for (int b = 0; b < W_BIT; ++b) {
    short8 af[4], bfr[4];
    #pragma unroll
    for (int mi = 0; mi < 4; ++mi) {
      short8 v = *(const short8*)&ub[((size_t)b * OUT_F + o0 + wm + mi * 16 + l16) * RANK + koff];
      af[mi] = qlo ? v : zf;
    }
    #pragma unroll
    for (int ni = 0; ni < 4; ++ni) {
      short8 v = *(const short8*)&vtT[((size_t)b * IN_F + i0 + wn + ni * 16 + l16) * RANK + koff];
      bfr[ni] = qlo ? v : zf;
    }

    #pragma unroll
    for (int mi = 0; mi < 4; ++mi) {
      floatx4 p[4];
      #pragma unroll
      for (int ni = 0; ni < 4; ++ni)
        p[ni] = __builtin_amdgcn_mfma_f32_16x16x32_bf16(
            af[mi], bfr[ni], (floatx4){0.f, 0.f, 0.f, 0.f}, 0, 0, 0);
      // C layout: col = l16, row = q*4 + v4  [verified m89/m91]
      #pragma unroll
      for (int v4 = 0; v4 < 4; ++v4) {
        const int o_loc = wm + mi * 16 + q * 4 + v4;
        const int* qrow = &qs[(b * 128 + o_loc) * 20];
        #pragma unroll
        for (int ni = 0; ni < 4; ++ni) {
          int qv = qrow[qc_base + ni * 2];
          float pv = p[ni][v4];
          acc[mi * 4 + ni][v4] += ((qv >> bit) & 1) ? pv : -pv;
        }
      }
    }
  }

  // store: 16 consecutive lanes (l16) write 16 consecutive bf16 -> 32B segments
  #pragma unroll
  for (int mi = 0; mi < 4; ++mi) {
    #pragma unroll
    for (int v4 = 0; v4 < 4; ++v4) {
      const int o = o0 + wm + mi * 16 + q * 4 + v4;
      #pragma unroll
      for (int ni = 0; ni < 4; ++ni)
        w[(size_t)o * IN_F + i0 + wn + ni * 16 + l16] = f2bf(acc[mi * 4 + ni][v4]);
    }
  }
}

// ---------------- phase 2: y = x @ w^T  (bf16 MFMA, 2-blocks/CU de-phased ring) --------
// M=2048, N=11008, K=4096. BM=BN=128, BK=32. 256 threads = 4 waves (2Mx2N),
// wave tile 64x64 = 4x4 frags of 16x16x32; 16 MFMA per wave per step.
//
// Round-4 insight: two different intra-phase schedules gave IDENTICAL perf ->
// bottleneck is single-block lockstep (1 resident 144KB block): MFMA (621cyc) and
// LDS (704cyc) pipes serialize because all 8 waves burst through the same barrier
// phase together. Fix: 4-slot ring of 16KB slots = 64KB LDS -> TWO independent
// blocks per CU. Same waves/SIMD (2), but barrier-independent -> one block's MFMA
// burst overlaps the other's LDS/barrier phase.
//
// Per phase u (steady):
//   vmcnt(4)   // completes stage(u+1), issued 2 phases ago (latency covered);
//              // stage(u+2),(u+3-pending) stay in flight - NEVER drains mid-loop
//   barrier    // publish slot(u+1) residency
//   LDFR frags(u+1) -> alternate reg set   (8 x ds_read_b128)
//   STAGE(u+3) -> slot((u+3)%4) = slot((u-1)%4)
//   setprio(1); 16 MFMA on current set (zero LDS dep); setprio(0)
// Race proof: slot(u-1)'s readers (LDFR at phase u-2) completed via reg-dep before
// MFMA(u-1) at phase u-1, which precedes barrier u; STAGE issues after barrier u.
// Tail peels with exact waits 4/4/0. Swizzle identical to the verified map
// (0 conflicts measured): dest chunk = src ^ ((row>>1)&3), inverse on global src;
// row+64 preserves the term (64>>1 = 32 = 0 mod 4) so one qsrc serves both rounds.
// NO min-wave launch bound (round-2 lesson: reg cap -> 800MB scratch spill).
#define NSTEP (IN_F / 32)   // 128
#define SLOT  16384         // A 8KB + B 8KB
#define NSLOT 4
__global__ __launch_bounds__(256) void k_gemm_bt(const ushort_t* __restrict__ A,  // [2048][4096]
                                                 const ushort_t* __restrict__ B,  // [11008][4096]
                                                 float* __restrict__ C) {         // [2048][11008]
  __shared__ __attribute__((aligned(16))) char lds[NSLOT * SLOT];  // 64 KB
  const int tid = threadIdx.x;
  const int wg = (blockIdx.x & 7) * 172 + (blockIdx.x >> 3);  // bijective XCD swizzle (1376=8*172)
  const int bm = wg & 15;    // 16 M-tiles of 128 (fastest: blocks sharing B-tile adjacent)
  const int bn = wg >> 4;    // 86 N-tiles of 128
  const int lane = tid & 63, wv = tid >> 6;
  const int wm = wv >> 1, wn = wv & 1;      // wave grid 2(M) x 2(N), wave tile 64x64
  const int l16 = lane & 15, q = lane >> 4;
  const int sQ = q ^ ((l16 >> 1) & 3);      // read-side swizzled 16B-chunk slot (thread const)

  const size_t ar = (size_t)bm * 128, br = (size_t)bn * 128;
  // staging: tiles 128x32 = 512 chunks each; thread covers chunk tid (rows 0-63)
  // and chunk 256+tid (rows 64-127). chunk c: row=c>>2, dest slot16=c&3,
  // src k-chunk = slot ^ ((row>>1)&3); identical for both rounds (+64 rows).
  const int qsrc = (tid & 3) ^ ((tid >> 3) & 3);
  const ushort_t* Ae = A + (ar + (tid >> 2)) * IN_F + qsrc * 8;
  const ushort_t* Be = B + (br + (tid >> 2)) * IN_F + qsrc * 8;
  const int ldsoff = (tid & 192) * 16;      // wave-uniform dest base (HW adds lane*16)
  const int aFrag = (wm * 64 + l16) * 64 + sQ * 16;   // byte off within A region (+mi*1024)
  const int bFrag = (wn * 64 + l16) * 64 + sQ * 16;   // byte off within B region (+ni*1024)

  floatx4 acc[4][4];
  #pragma unroll
  for (int mi = 0; mi < 4; ++mi)
    #pragma unroll
    for (int ni = 0; ni < 4; ++ni) acc[mi][ni] = (floatx4){0.f, 0.f, 0.f, 0.f};

  short8 fa0[4], fb0[4], fa1[4], fb1[4];
  int sLd = SLOT;            // byte offset of slot holding frags(u+1) at phase u
  int sWr = 3 * SLOT;        // byte offset of slot receiving STAGE(u+3) at phase u

#define STAGEK(kt, off) do {                                                 \
    const size_t _k0 = (size_t)(kt) * 32;                                    \
    char* _d = lds + (off) + ldsoff;                                         \
    gl_lds16(Ae + _k0,                _d);                                   \
    gl_lds16(Ae + 64 * IN_F + _k0,    _d + 4096);                            \
    gl_lds16(Be + _k0,                _d + 8192);                            \
    gl_lds16(Be + 64 * IN_F + _k0,    _d + 12288);                           \
  } while (0)

#define LDFR(FA, FB, off) do {                                               \
    const char* _ab = lds + (off);                                           \
    const char* _bb = _ab + 8192;                                            \
    _Pragma("unroll") for (int mi = 0; mi < 4; ++mi)                         \
      FA[mi] = *(const short8*)(_ab + aFrag + mi * 1024);                    \
    _Pragma("unroll") for (int ni = 0; ni < 4; ++ni)                         \
      FB[ni] = *(const short8*)(_bb + bFrag + ni * 1024);                    \
  } while (0)

#define MFMA16(MA, MB) do {                                                  \
    __builtin_amdgcn_s_setprio(1);                                           \
    _Pragma("unroll") for (int mi = 0; mi < 4; ++mi)                         \
      _Pragma("unroll") for (int ni = 0; ni < 4; ++ni)                       \
        acc[mi][ni] = __builtin_amdgcn_mfma_f32_16x16x32_bf16(               \
            MA[mi], MB[ni], acc[mi][ni], 0, 0, 0);                           \
    __builtin_amdgcn_s_setprio(0);                                           \
  } while (0)

#define PHASE(u_, VM, DO_STAGE, FA, FB, MA, MB) do {                         \
    asm volatile(VM ::: "memory");                                           \
    __builtin_amdgcn_s_barrier();                                            \
    asm volatile("" ::: "memory");                                           \
    LDFR(FA, FB, sLd);                   /* frags of step u_+1, alt set */   \
    if (DO_STAGE) STAGEK((u_) + 3, sWr);                                     \
    MFMA16(MA, MB);                      /* step u_, zero LDS dependency */  \
    sLd += SLOT; if (sLd == NSLOT * SLOT) sLd = 0;                           \
    sWr += SLOT; if (sWr == NSLOT * SLOT) sWr = 0;                           \
  } while (0)

  // prologue: stage steps 0..2 into slots 0..2 (12 loads out), frags(0) -> set0
  STAGEK(0, 0); STAGEK(1, SLOT); STAGEK(2, 2 * SLOT);
  asm volatile("s_waitcnt vmcnt(8)" ::: "memory");
  __builtin_amdgcn_s_barrier();
  asm volatile("" ::: "memory");
  LDFR(fa0, fb0, 0);

  // steady: phases u=0..123, stage u+3 (covers 3..126), wait vmcnt(4)
  for (int u = 0; u < NSTEP - 4; u += 2) {
    PHASE(u,     "s_waitcnt vmcnt(4)", true, fa1, fb1, fa0, fb0);
    PHASE(u + 1, "s_waitcnt vmcnt(4)", true, fa0, fb0, fa1, fb1);
  }
  // phase 124: stage 127 (last); phases 125/126 shrink waits 4/0; 127 MFMA-only
  PHASE(NSTEP - 4, "s_waitcnt vmcnt(4)", true,  fa1, fb1, fa0, fb0);
  PHASE(NSTEP - 3, "s_waitcnt vmcnt(4)", false, fa0, fb0, fa1, fb1);
  PHASE(NSTEP - 2, "s_waitcnt vmcnt(0)", false, fa1, fb1, fa0, fb0);
  MFMA16(fa1, fb1);                      // step 127 (frags loaded in phase 126)

#undef STAGEK
#undef LDFR
#undef MFMA16
#undef PHASE

  // C/D layout: col = lane&15, row = (lane>>4)*4 + reg  [verified m89/m91]
  #pragma unroll
  for (int mi = 0; mi < 4; ++mi) {
    #pragma unroll
    for (int ni = 0; ni < 4; ++ni) {
      #pragma unroll
      for (int v = 0; v < 4; ++v) {
        int r = bm * 128 + wm * 64 + mi * 16 + q * 4 + v;
        int c = bn * 128 + wn * 64 + ni * 16 + l16;
        C[(size_t)r * OUT_F + c] = acc[mi][ni][v];
      }
    }
  }
}

extern "C" void kernel_launch(void* const* d_in, const int* in_sizes, int n_in,
                              void* d_out, int out_size, void* d_ws, size_t ws_size,
                              hipStream_t stream) {
  (void)in_sizes; (void)n_in; (void)out_size; (void)ws_size;
  const float* x  = (const float*)d_in[0];
  const int*   qw = (const int*)d_in[1];
  const float* u  = (const float*)d_in[2];
  const float* vt = (const float*)d_in[3];
  float* out = (float*)d_out;

  // workspace layout (bytes):
  //   xb  @ 0         : 2048*4096*2   = 16,777,216
  //   wb  @ 16.0 MB   : 11008*4096*2  = 90,177,536
  //   ub  @ 102.0 MB  : 4*11008*16*2  = 1,409,024
  //   vtT @ 103.3 MB  : 4*4096*16*2   = 524,288     (total ~103.8 MiB)
  char* wsp = (char*)d_ws;
  ushort_t* xb  = (ushort_t*)wsp;
  ushort_t* wb  = (ushort_t*)(wsp + (size_t)TOKENS * IN_F * 2);
  ushort_t* ubf = (ushort_t*)(wsp + (size_t)TOKENS * IN_F * 2 + (size_t)OUT_F * IN_F * 2);
  ushort_t* vtT = (ushort_t*)(wsp + (size_t)TOKENS * IN_F * 2 + (size_t)OUT_F * IN_F * 2 +
                              (size_t)N_U * 2);

  k_cvt_x<<<TOKENS * IN_F / 1024, 256, 0, stream>>>(x, xb);
  k_prep_uv<<<(N_U + N_VT) / 256, 256, 0, stream>>>(u, vt, ubf, vtT);
  k_build_w<<<(OUT_F / 128) * (IN_F / 128), 256, 0, stream>>>(qw, ubf, vtT, wb);
  k_gemm_bt<<<16 * (OUT_F / 128), 256, 0, stream>>>(xb, wb, out);
}

// Round 8
// 422.083 us; speedup vs baseline: 1.0619x; 1.0619x over previous
//
#include <hip/hip_runtime.h>
#include <cstdint>
#include <cstddef>

// Problem constants (from reference)
#define TOKENS 2048
#define IN_F   4096
#define OUT_F  11008
#define W_BIT  4
#define RANK   16
#define QWB    (OUT_F * IN_F / 8)   // 5,636,096 int32 "bytes" per bit-plane

typedef unsigned short ushort_t;
typedef __attribute__((ext_vector_type(8))) short   short8;   // 8 bf16 = 4 VGPRs (MFMA A/B frag)
typedef __attribute__((ext_vector_type(4))) float   floatx4;  // MFMA C/D frag

__device__ __forceinline__ ushort_t f2bf(float f) {
  union { float f; uint32_t u; } c; c.f = f;
  uint32_t r = c.u + 0x7FFFu + ((c.u >> 16) & 1u);  // RNE
  return (ushort_t)(r >> 16);
}

// async global->LDS, 16B per lane; lds pointer must be wave-uniform base (HW adds lane*16)
__device__ __forceinline__ void gl_lds16(const void* g, void* l) {
  __builtin_amdgcn_global_load_lds(
      (const __attribute__((address_space(1))) uint32_t*)g,
      (__attribute__((address_space(3))) uint32_t*)l, 16, 0, 0);
}

// ---------------- phase 0a: x fp32 -> bf16 ----------------
__global__ __launch_bounds__(256) void k_cvt_x(const float* __restrict__ x,
                                               ushort_t* __restrict__ xb) {
  int idx = blockIdx.x * 256 + threadIdx.x;
  float4 v = ((const float4*)x)[idx];
  ushort4 r;
  r.x = f2bf(v.x); r.y = f2bf(v.y); r.z = f2bf(v.z); r.w = f2bf(v.w);
  ((ushort4*)xb)[idx] = r;
}

// ---------------- phase 0b: u -> bf16 (same layout), vt -> bf16 transposed ----------------
#define N_U  (W_BIT * OUT_F * RANK)   // 704512
#define N_VT (W_BIT * RANK * IN_F)    // 262144
__global__ __launch_bounds__(256) void k_prep_uv(const float* __restrict__ u,
                                                 const float* __restrict__ vt,
                                                 ushort_t* __restrict__ ub,
                                                 ushort_t* __restrict__ vtT) {
  int idx = blockIdx.x * 256 + threadIdx.x;
  if (idx < N_U) {
    ub[idx] = f2bf(u[idx]);
  } else {
    int e = idx - N_U;                 // [0, N_VT)
    int b = e >> 16;                   // RANK*IN_F = 65536
    int r = e & 65535;
    int k = r >> 12;                   // IN_F = 4096
    int i = r & 4095;
    vtT[((size_t)b * IN_F + i) * RANK + k] = f2bf(vt[e]);
  }
}

// ---------------- phase 1: build w (bf16): MFMA product + LDS-staged sign apply ----
// Round-0 version, verbatim (best measured). Do NOT edit blind.
__global__ __launch_bounds__(256) void k_build_w(const int* __restrict__ qw,
                                                 const ushort_t* __restrict__ ub,
                                                 const ushort_t* __restrict__ vtT,
                                                 ushort_t* __restrict__ w) {
  __shared__ int qs[W_BIT * 128 * 20];  // 40 KB
  const int tid = threadIdx.x;
  const int ob = blockIdx.x / (IN_F / 128);
  const int ib = blockIdx.x % (IN_F / 128);
  const int o0 = ob * 128, i0 = ib * 128;
  const int lane = tid & 63, wv = tid >> 6;
  const int wm = (wv >> 1) * 64, wn = (wv & 1) * 64;
  const int l16 = lane & 15, q = lane >> 4;
  const bool qlo = (q < 2);
  const int koff = (q & 1) * 8;        // valid k-halves for q=0,1; q>=2 zeroed
  const short8 zf = (short8)0;

  // stage qw tile: 4 planes x 128 rows x 16 ints; 2048 int4 chunks, 8/thread, coalesced
  #pragma unroll
  for (int n = 0; n < 8; ++n) {
    int c = n * 256 + tid;             // [0, 2048)
    int b = c >> 9, rem = c & 511;
    int row = rem >> 2, part = rem & 3;
    int4 v = *(const int4*)(qw + (size_t)b * QWB +
                            (size_t)(o0 + row) * (IN_F / 8) + (i0 >> 3) + part * 4);
    *(int4*)&qs[(b * 128 + row) * 20 + part * 4] = v;
  }

  floatx4 acc[16];
  #pragma unroll
  for (int i = 0; i < 16; ++i) acc[i] = (floatx4){0.f, 0.f, 0.f, 0.f};

  const int qc_base = (wn >> 3) + (l16 >> 3);  // LDS int col for this lane (+ni*2)
  const int bit = l16 & 7;

  __syncthreads();

  #pragma unroll
  for (int b = 0; b < W_BIT; ++b) {
    short8 af[4], bfr[4];
    #pragma unroll
    for (int mi = 0; mi < 4; ++mi) {
      short8 v = *(const short8*)&ub[((size_t)b * OUT_F + o0 + wm + mi * 16 + l16) * RANK + koff];
      af[mi] = qlo ? v : zf;
    }
    #pragma unroll
    for (int ni = 0; ni < 4; ++ni) {
      short8 v = *(const short8*)&vtT[((size_t)b * IN_F + i0 + wn + ni * 16 + l16) * RANK + koff];
      bfr[ni] = qlo ? v : zf;
    }

    #pragma unroll
    for (int mi = 0; mi < 4; ++mi) {
      floatx4 p[4];
      #pragma unroll
      for (int ni = 0; ni < 4; ++ni)
        p[ni] = __builtin_amdgcn_mfma_f32_16x16x32_bf16(
            af[mi], bfr[ni], (floatx4){0.f, 0.f, 0.f, 0.f}, 0, 0, 0);
      // C layout: col = l16, row = q*4 + v4  [verified m89/m91]
      #pragma unroll
      for (int v4 = 0; v4 < 4; ++v4) {
        const int o_loc = wm + mi * 16 + q * 4 + v4;
        const int* qrow = &qs[(b * 128 + o_loc) * 20];
        #pragma unroll
        for (int ni = 0; ni < 4; ++ni) {
          int qv = qrow[qc_base + ni * 2];
          float pv = p[ni][v4];
          acc[mi * 4 + ni][v4] += ((qv >> bit) & 1) ? pv : -pv;
        }
      }
    }
  }

  // store: 16 consecutive lanes (l16) write 16 consecutive bf16 -> 32B segments
  #pragma unroll
  for (int mi = 0; mi < 4; ++mi) {
    #pragma unroll
    for (int v4 = 0; v4 < 4; ++v4) {
      const int o = o0 + wm + mi * 16 + q * 4 + v4;
      #pragma unroll
      for (int ni = 0; ni < 4; ++ni)
        w[(size_t)o * IN_F + i0 + wn + ni * 16 + l16] = f2bf(acc[mi * 4 + ni][v4]);
    }
  }
}

// ---------------- phase 2: y = x @ w^T  (bf16 MFMA, 128x64 wave tile, LDS-lean) --------
// M=2048, N=11008, K=4096. BM=256, BN=128, BK=32. 256 threads = 4 waves (2Mx2N),
// wave tile 128x64 = 8x4 frags of 16x16x32; 32 MFMA per wave per step.
//
// Rounds 1-7 unified diagnosis: all prior configs were LDS-BANDWIDTH-bound:
// per CU per K-step, MFMA issue = 621 cyc but LDS traffic (reads+stage writes)
// = 687-750 cyc at a 64x64 wave tile -> schedule tweaks (reg-dbuf r4, block
// de-phasing r7) were neutral/negative because the LDS port was the binding
// resource. 128x64 wave tile: reads 12KB/32 MFMA (vs 8KB/16), block 256x128
// halves stage-writes per FLOP. New per-CU ledger (2 blocks resident):
// LDS = 96KB read + 48KB write = 1125 cyc < MFMA 1242 cyc -> MFMA is now
// the longer pole.
//
// 3-slot ring (3 x 24KB = 72KB LDS -> 2 blocks/CU, 8 waves, 2/SIMD).
// Per phase u:
//   vmcnt(6)   // completes stage(u) (6 loads; stage(u+1) stays in flight)
//   barrier    // publish slot(u) residency
//   LDFR frags(u): 12 x ds_read_b128 (A 8, B 4)
//   STAGE(u+2) -> slot((u+2)%3) = slot((u-1)%3)   [6 x gl_lds16]
//   setprio(1); 32 MFMA; setprio(0)
// Ledger: prologue stages 0,1 (12 out); steady entering = 12, wait->6, stage->12.
// Tail: phase 126 vmcnt(6) no stage (out 6); phase 127 vmcnt(0).
// Race proof: slot(u-1)'s readers (LDFR at u-1) complete via reg-dep before
// MFMA(u-1), which precedes barrier u; STAGE issues after barrier u. Writes:
// stage(u-1) into that slot completed at phase u-1's vmcnt.
// Swizzle: verified map (0 conflicts r1/r3/r4/r7): dest chunk = src ^ ((row>>1)&3),
// inverse folded into per-lane GLOBAL source; row offsets {64,128,192} preserve
// the term (all ≡ 0 mod 8 after >>1&3).
// __launch_bounds__(256,2): caps VGPR at 256 (est. need ~210; 56-reg margin --
// NOT r2's fatal 128 cap) so 2 blocks/CU are guaranteed.
#define NSTEP (IN_F / 32)   // 128
#define SLOT  24576         // A 16KB + B 8KB
#define NSLOT 3
__global__ __launch_bounds__(256, 2) void k_gemm_bt(const ushort_t* __restrict__ A,  // [2048][4096]
                                                    const ushort_t* __restrict__ B,  // [11008][4096]
                                                    float* __restrict__ C) {         // [2048][11008]
  __shared__ __attribute__((aligned(16))) char lds[NSLOT * SLOT];  // 72 KB
  const int tid = threadIdx.x;
  const int wg = (blockIdx.x & 7) * 86 + (blockIdx.x >> 3);  // bijective XCD swizzle (688=8*86)
  const int bm = wg & 7;     // 8 M-tiles of 256 (fastest: adjacent wg share B-panel)
  const int bn = wg >> 3;    // 86 N-tiles of 128
  const int lane = tid & 63, wv = tid >> 6;
  const int wm = wv >> 1, wn = wv & 1;      // wave grid 2(M) x 2(N), wave tile 128x64
  const int l16 = lane & 15, q = lane >> 4;
  const int sQ = q ^ ((l16 >> 1) & 3);      // read-side swizzled 16B-chunk slot (thread const)

  const size_t ar = (size_t)bm * 256, br = (size_t)bn * 128;
  // staging (256 thr): A 256x32 = 1024 chunks (4 loads: rows tid>>2 + {0,64,128,192});
  // B 128x32 = 512 chunks (2 loads: rows tid>>2 + {0,64}).
  // chunk c: row=c>>2, dest16=c&3, src k-chunk = (c&3) ^ ((row>>1)&3);
  // row base advances by 64 -> (row>>1)&3 term invariant -> one qsrc for all loads.
  const int qsrc = (tid & 3) ^ ((tid >> 3) & 3);
  const ushort_t* Ae = A + (ar + (tid >> 2)) * IN_F + qsrc * 8;
  const ushort_t* Be = B + (br + (tid >> 2)) * IN_F + qsrc * 8;
  const int ldsoff = (tid & 192) * 16;      // wave-uniform dest base (HW adds lane*16)
  const int aFrag = (wm * 128 + l16) * 64 + sQ * 16;  // byte off within A region (+mi*1024)
  const int bFrag = (wn * 64 + l16) * 64 + sQ * 16;   // byte off within B region (+ni*1024)

  floatx4 acc[8][4];
  #pragma unroll
  for (int mi = 0; mi < 8; ++mi)
    #pragma unroll
    for (int ni = 0; ni < 4; ++ni) acc[mi][ni] = (floatx4){0.f, 0.f, 0.f, 0.f};

  short8 af[8], bf[4];
  int sLd = 0;               // byte offset of slot holding frags(u) at phase u
  int sWr = 2 * SLOT;        // byte offset of slot receiving STAGE(u+2) at phase u

#define STAGEK(kt, off) do {                                                 \
    const size_t _k0 = (size_t)(kt) * 32;                                    \
    char* _d = lds + (off) + ldsoff;                                         \
    gl_lds16(Ae + _k0,                 _d);                                  \
    gl_lds16(Ae +  64 * IN_F + _k0,    _d + 4096);                           \
    gl_lds16(Ae + 128 * IN_F + _k0,    _d + 8192);                           \
    gl_lds16(Ae + 192 * IN_F + _k0,    _d + 12288);                          \
    gl_lds16(Be + _k0,                 _d + 16384);                          \
    gl_lds16(Be +  64 * IN_F + _k0,    _d + 20480);                          \
  } while (0)

#define PHASE(u_, VM, DO_STAGE) do {                                         \
    asm volatile(VM ::: "memory");                                           \
    __builtin_amdgcn_s_barrier();                                            \
    asm volatile("" ::: "memory");                                           \
    {                                                                        \
      const char* _ab = lds + sLd;                                           \
      const char* _bb = _ab + 16384;                                         \
      _Pragma("unroll") for (int mi = 0; mi < 8; ++mi)                       \
        af[mi] = *(const short8*)(_ab + aFrag + mi * 1024);                  \
      _Pragma("unroll") for (int ni = 0; ni < 4; ++ni)                       \
        bf[ni] = *(const short8*)(_bb + bFrag + ni * 1024);                  \
    }                                                                        \
    if (DO_STAGE) STAGEK((u_) + 2, sWr);                                     \
    __builtin_amdgcn_s_setprio(1);                                           \
    _Pragma("unroll") for (int mi = 0; mi < 8; ++mi)                         \
      _Pragma("unroll") for (int ni = 0; ni < 4; ++ni)                       \
        acc[mi][ni] = __builtin_amdgcn_mfma_f32_16x16x32_bf16(               \
            af[mi], bf[ni], acc[mi][ni], 0, 0, 0);                           \
    __builtin_amdgcn_s_setprio(0);                                           \
    sLd += SLOT; if (sLd == NSLOT * SLOT) sLd = 0;                           \
    sWr += SLOT; if (sWr == NSLOT * SLOT) sWr = 0;                           \
  } while (0)

  // prologue: stage steps 0,1 into slots 0,1 (12 loads in flight)
  STAGEK(0, 0); STAGEK(1, SLOT);

  // steady: phases 0..125 stage u+2 (covers 2..127), wait vmcnt(6)
  for (int u = 0; u < NSTEP - 2; ++u)
    PHASE(u, "s_waitcnt vmcnt(6)", true);
  // tail: 126 (stage 127 resident after wait 6... completes stage 126; stage 127 in flight)
  PHASE(NSTEP - 2, "s_waitcnt vmcnt(6)", false);
  PHASE(NSTEP - 1, "s_waitcnt vmcnt(0)", false);

#undef STAGEK
#undef PHASE

  // C/D layout: col = lane&15, row = (lane>>4)*4 + reg  [verified m89/m91]
  #pragma unroll
  for (int mi = 0; mi < 8; ++mi) {
    #pragma unroll
    for (int ni = 0; ni < 4; ++ni) {
      #pragma unroll
      for (int v = 0; v < 4; ++v) {
        int r = bm * 256 + wm * 128 + mi * 16 + q * 4 + v;
        int c = bn * 128 + wn * 64 + ni * 16 + l16;
        C[(size_t)r * OUT_F + c] = acc[mi][ni][v];
      }
    }
  }
}

extern "C" void kernel_launch(void* const* d_in, const int* in_sizes, int n_in,
                              void* d_out, int out_size, void* d_ws, size_t ws_size,
                              hipStream_t stream) {
  (void)in_sizes; (void)n_in; (void)out_size; (void)ws_size;
  const float* x  = (const float*)d_in[0];
  const int*   qw = (const int*)d_in[1];
  const float* u  = (const float*)d_in[2];
  const float* vt = (const float*)d_in[3];
  float* out = (float*)d_out;

  // workspace layout (bytes):
  //   xb  @ 0         : 2048*4096*2   = 16,777,216
  //   wb  @ 16.0 MB   : 11008*4096*2  = 90,177,536
  //   ub  @ 102.0 MB  : 4*11008*16*2  = 1,409,024
  //   vtT @ 103.3 MB  : 4*4096*16*2   = 524,288     (total ~103.8 MiB)
  char* wsp = (char*)d_ws;
  ushort_t* xb  = (ushort_t*)wsp;
  ushort_t* wb  = (ushort_t*)(wsp + (size_t)TOKENS * IN_F * 2);
  ushort_t* ubf = (ushort_t*)(wsp + (size_t)TOKENS * IN_F * 2 + (size_t)OUT_F * IN_F * 2);
  ushort_t* vtT = (ushort_t*)(wsp + (size_t)TOKENS * IN_F * 2 + (size_t)OUT_F * IN_F * 2 +
                              (size_t)N_U * 2);

  k_cvt_x<<<TOKENS * IN_F / 1024, 256, 0, stream>>>(x, xb);
  k_prep_uv<<<(N_U + N_VT) / 256, 256, 0, stream>>>(u, vt, ubf, vtT);
  k_build_w<<<(OUT_F / 128) * (IN_F / 128), 256, 0, stream>>>(qw, ubf, vtT, wb);
  k_gemm_bt<<<8 * (OUT_F / 128), 256, 0, stream>>>(xb, wb, out);
}